// Round 2
// baseline (119.356 us; speedup 1.0000x reference)
//
#include <hip/hip_runtime.h>

// Geometric product in Cl(3,2,1), DIM=64.
// out[n,k] = sum_a sign(a, a^k) * x[n,a] * y[n,a^k]
// Signs are compile-time constants folded into FMA negate modifiers; zero
// terms (null-dim annihilation) are dead-code-eliminated.

__host__ __device__ constexpr int popc6(int v) {
  int c = 0;
  for (int i = 0; i < 6; ++i) c += (v >> i) & 1;
  return c;
}

// Faithful to reference _cayley_tables(3,2,1):
//  - swap parity: for each bit set in a, count set bits of b below that bit
//  - neg dims: bits 3,4 (e3^2 = e4^2 = -1)
//  - null dim: bit 5 (e5^2 = 0)
__host__ __device__ constexpr float sign_ab(int a, int b) {
  int swap = 0;
  for (int bit = 0; bit < 6; ++bit)
    if ((a >> bit) & 1) swap += popc6(b & ((1 << bit) - 1));
  float s = (swap & 1) ? -1.0f : 1.0f;
  if (popc6(a & b & 0x18) & 1) s = -s;  // negative dims: bits 3,4
  if (a & b & 0x20) s = 0.0f;           // null dim: bit 5
  return s;
}

struct SignTab {
  float s[64][64];
  constexpr SignTab() : s{} {
    for (int a = 0; a < 64; ++a)
      for (int b = 0; b < 64; ++b) s[a][b] = sign_ab(a, b);
  }
};
static constexpr SignTab TAB{};

// Wave q owns k in {Q, Q+4, ..., Q+60}. Plain unrolled loops: after full
// unroll every TAB index is a constant -> clang folds s to +/-1 or 0.
template <int Q>
__device__ __forceinline__ void compute(const float* __restrict__ xrow,
                                        const float (&yv)[64], float (&acc)[16]) {
#pragma unroll
  for (int a = 0; a < 64; ++a) {
    const float xa = xrow[a];  // ds_read_b32, stride-65 row -> 2-way bank (free)
#pragma unroll
    for (int kk = 0; kk < 16; ++kk) {
      const int k = Q + 4 * kk;
      const int b = a ^ k;
      const float s = TAB.s[a][b];          // constant-folded
      acc[kk] = fmaf(s * xa, yv[b], acc[kk]);  // s=+1/-1 -> fneg modifier; s=0 -> DCE
    }
  }
}

__global__ __launch_bounds__(256, 4) void clgp_kernel(const float* __restrict__ xg,
                                                      const float* __restrict__ yg,
                                                      float* __restrict__ og) {
  // LDS tiles padded to stride 65 floats (65 % 32 == 1 -> scalar row reads are
  // 2-way bank-aliased = free; stride 64 would be a 32-way conflict).
  __shared__ float xl[64 * 65];
  __shared__ float yl[64 * 65];

  const int t = threadIdx.x;
  const long tile = (long)blockIdx.x * 4096;  // 64 rows * 64 cols (floats)

  // ---- stage x,y: coalesced global float4 -> reg -> padded LDS ----
  const float4* x4 = (const float4*)(xg + tile);
  const float4* y4 = (const float4*)(yg + tile);
  float4 rx[4], ry[4];
#pragma unroll
  for (int p = 0; p < 4; ++p) {
    rx[p] = x4[t + p * 256];
    ry[p] = y4[t + p * 256];
  }
#pragma unroll
  for (int p = 0; p < 4; ++p) {
    const int v = t + p * 256;               // float4 index within tile
    const int w = (v >> 4) * 65 + (v & 15) * 4;
    xl[w + 0] = rx[p].x; xl[w + 1] = rx[p].y; xl[w + 2] = rx[p].z; xl[w + 3] = rx[p].w;
    yl[w + 0] = ry[p].x; yl[w + 1] = ry[p].y; yl[w + 2] = ry[p].z; yl[w + 3] = ry[p].w;
  }
  __syncthreads();

  const int lane = t & 63;  // batch row within tile
  const int q = t >> 6;     // wave id = k residue class mod 4 (wave-uniform)

  // y row -> 64 registers (scalar LDS reads, 2-way bank-aliased = free)
  float yv[64];
  {
    const float* yrow = &yl[lane * 65];
#pragma unroll
    for (int j = 0; j < 64; ++j) yv[j] = yrow[j];
  }

  float acc[16];
#pragma unroll
  for (int i = 0; i < 16; ++i) acc[i] = 0.0f;

  const float* xrow = &xl[lane * 65];
  switch (q) {  // wave-uniform branch -> no divergence
    case 0: compute<0>(xrow, yv, acc); break;
    case 1: compute<1>(xrow, yv, acc); break;
    case 2: compute<2>(xrow, yv, acc); break;
    default: compute<3>(xrow, yv, acc); break;
  }

  __syncthreads();  // all waves done reading xl
  // transpose acc back through LDS (reuse xl) for coalesced stores
#pragma unroll
  for (int kk = 0; kk < 16; ++kk) xl[lane * 65 + q + 4 * kk] = acc[kk];
  __syncthreads();

  float4* o4 = (float4*)(og + tile);
#pragma unroll
  for (int p = 0; p < 4; ++p) {
    const int v = t + p * 256;
    const int w = (v >> 4) * 65 + (v & 15) * 4;
    float4 o;
    o.x = xl[w + 0]; o.y = xl[w + 1]; o.z = xl[w + 2]; o.w = xl[w + 3];
    o4[v] = o;
  }
}

extern "C" void kernel_launch(void* const* d_in, const int* in_sizes, int n_in,
                              void* d_out, int out_size, void* d_ws, size_t ws_size,
                              hipStream_t stream) {
  const float* x = (const float*)d_in[0];
  const float* y = (const float*)d_in[1];
  float* out = (float*)d_out;
  const int n_batch = in_sizes[0] / 64;
  const int grid = n_batch / 64;  // 65536/64 = 1024 blocks, 256 threads each
  clgp_kernel<<<grid, 256, 0, stream>>>(x, y, out);
}

// Round 3
// 73.988 us; speedup vs baseline: 1.6132x; 1.6132x over previous
//
#include <hip/hip_runtime.h>
#include <utility>

// Geometric product in Cl(3,2,1), DIM=64.
// out[n,k] = sum_a sign(a, a^k) * x[n,a] * y[n,a^k]
// All sign logic at compile time via template-parameter indices (fold
// expressions -> guaranteed full unroll, guaranteed constant array indices).

__host__ __device__ constexpr int popc6(int v) {
  int c = 0;
  for (int i = 0; i < 6; ++i) c += (v >> i) & 1;
  return c;
}

// Faithful to reference _cayley_tables(3,2,1):
//  - swap parity: for each bit set in a, count set bits of b below that bit
//  - neg dims: bits 3,4 (e3^2 = e4^2 = -1)
//  - null dim: bit 5 (e5^2 = 0)
__host__ __device__ constexpr float sign_ab(int a, int b) {
  int sw = 0;
  for (int bit = 0; bit < 6; ++bit)
    if ((a >> bit) & 1) sw += popc6(b & ((1 << bit) - 1));
  float s = (sw & 1) ? -1.0f : 1.0f;
  if (popc6(a & b & 0x18) & 1) s = -s;  // negative dims: bits 3,4
  if (a & b & 0x20) s = 0.0f;           // null dim: bit 5
  return s;
}

// One FMA term: k = Q + 4*KK (wave q owns k === q mod 4; balanced: every wave
// gets 8 k's with bit5=0 and 8 with bit5=1 -> 768 live FMAs per thread).
template <int Q, int A, int KK>
__device__ __forceinline__ void term(float xa, const float (&yv)[64], float (&acc)[16]) {
  constexpr int k = Q + 4 * KK;
  constexpr int b = A ^ k;
  constexpr float sg = sign_ab(A, b);
  if constexpr (sg > 0.0f)      acc[KK] = fmaf( xa, yv[b], acc[KK]);
  else if constexpr (sg < 0.0f) acc[KK] = fmaf(-xa, yv[b], acc[KK]);
  // sg == 0: no code
}

template <int Q, int A, int... KK>
__device__ __forceinline__ void terms(float xa, const float (&yv)[64], float (&acc)[16],
                                      std::integer_sequence<int, KK...>) {
  (term<Q, A, KK>(xa, yv, acc), ...);
}

template <int Q, int A>
__device__ __forceinline__ void run_a(const float* __restrict__ xrow, const float (&yv)[64],
                                      float (&acc)[16]) {
  terms<Q, A>(xrow[A], yv, acc, std::make_integer_sequence<int, 16>{});
}

template <int Q, int... As>
__device__ __forceinline__ void run_all(const float* __restrict__ xrow, const float (&yv)[64],
                                        float (&acc)[16], std::integer_sequence<int, As...>) {
  (run_a<Q, As>(xrow, yv, acc), ...);
}

__global__ void clgp_kernel(const float* __restrict__ xg,
                            const float* __restrict__ yg,
                            float* __restrict__ og) {
  // Stride-65 rows: 65 % 32 == 1 -> per-lane scalar row reads are 2-way
  // bank-aliased (free, m136); stride 64 would be a 32-way conflict.
  __shared__ float xl[64 * 65];
  __shared__ float yl[64 * 65];

  const int t = threadIdx.x;
  const long tile = (long)blockIdx.x * 4096;  // 64 rows * 64 cols

  // ---- stage x,y: coalesced global float4 -> reg -> padded LDS ----
  const float4* x4 = (const float4*)(xg + tile);
  const float4* y4 = (const float4*)(yg + tile);
  float4 rx[4], ry[4];
#pragma unroll
  for (int p = 0; p < 4; ++p) {
    rx[p] = x4[t + p * 256];
    ry[p] = y4[t + p * 256];
  }
#pragma unroll
  for (int p = 0; p < 4; ++p) {
    const int v = t + p * 256;               // float4 index within tile
    const int w = (v >> 4) * 65 + (v & 15) * 4;
    xl[w + 0] = rx[p].x; xl[w + 1] = rx[p].y; xl[w + 2] = rx[p].z; xl[w + 3] = rx[p].w;
    yl[w + 0] = ry[p].x; yl[w + 1] = ry[p].y; yl[w + 2] = ry[p].z; yl[w + 3] = ry[p].w;
  }
  __syncthreads();

  const int lane = t & 63;  // batch row within tile
  const int q = t >> 6;     // wave id = k residue class mod 4 (wave-uniform)

  // y row -> 64 registers (scalar ds_read, constant offsets, 2-way bank = free)
  float yv[64];
  const float* yrow = &yl[lane * 65];
#pragma unroll
  for (int j = 0; j < 64; ++j) yv[j] = yrow[j];

  float acc[16];
#pragma unroll
  for (int i = 0; i < 16; ++i) acc[i] = 0.0f;

  const float* xrow = &xl[lane * 65];
  switch (q) {  // wave-uniform -> no divergence
    case 0:  run_all<0>(xrow, yv, acc, std::make_integer_sequence<int, 64>{}); break;
    case 1:  run_all<1>(xrow, yv, acc, std::make_integer_sequence<int, 64>{}); break;
    case 2:  run_all<2>(xrow, yv, acc, std::make_integer_sequence<int, 64>{}); break;
    default: run_all<3>(xrow, yv, acc, std::make_integer_sequence<int, 64>{}); break;
  }

  __syncthreads();  // all waves done reading xl
  // transpose acc back through LDS (reuse xl) for coalesced float4 stores
#pragma unroll
  for (int kk = 0; kk < 16; ++kk) xl[lane * 65 + q + 4 * kk] = acc[kk];
  __syncthreads();

  float4* o4 = (float4*)(og + tile);
#pragma unroll
  for (int p = 0; p < 4; ++p) {
    const int v = t + p * 256;
    const int w = (v >> 4) * 65 + (v & 15) * 4;
    float4 o;
    o.x = xl[w + 0]; o.y = xl[w + 1]; o.z = xl[w + 2]; o.w = xl[w + 3];
    o4[v] = o;
  }
}

extern "C" void kernel_launch(void* const* d_in, const int* in_sizes, int n_in,
                              void* d_out, int out_size, void* d_ws, size_t ws_size,
                              hipStream_t stream) {
  const float* x = (const float*)d_in[0];
  const float* y = (const float*)d_in[1];
  float* out = (float*)d_out;
  const int n_batch = in_sizes[0] / 64;
  const int grid = n_batch / 64;  // 65536/64 = 1024 blocks, 256 threads
  clgp_kernel<<<grid, 256, 0, stream>>>(x, y, out);
}

// Round 4
// 16.600 us; speedup vs baseline: 7.1899x; 4.4570x over previous
//
#include <hip/hip_runtime.h>
#include <utility>

// Geometric product in Cl(3,2,1), DIM=64.
// out[n,k] = sum_a sign(a, a^k) * x[n,a] * y[n,a^k]
//
// xor-nibble decomposition: k = 4*kk + q, a = 4*ah + al  =>
//   b = a^k = 4*(ah^kk) + (al^q)
// For fixed (al, q): acc[kk] += sign * x[4*ah+al] * yr[ah^kk] where
// yr[h] = y[4*h + (al^q)] -- a 16x16 xor-convolution in the high nibble.
// Peak live regs: 16 acc + 16 yr + 1 x + addr ~= 40  (fits 64-VGPR budget,
// no spill by construction; rounds 1-3 spilled ~80+ regs to scratch).

__host__ __device__ constexpr int popc6(int v) {
  int c = 0;
  for (int i = 0; i < 6; ++i) c += (v >> i) & 1;
  return c;
}

// Faithful to reference _cayley_tables(3,2,1):
//  - swap parity: for each bit set in a, count set bits of b below that bit
//  - neg dims: bits 3,4 (e3^2 = e4^2 = -1)
//  - null dim: bit 5 (e5^2 = 0)
__host__ __device__ constexpr float sign_ab(int a, int b) {
  int sw = 0;
  for (int bit = 0; bit < 6; ++bit)
    if ((a >> bit) & 1) sw += popc6(b & ((1 << bit) - 1));
  float s = (sw & 1) ? -1.0f : 1.0f;
  if (popc6(a & b & 0x18) & 1) s = -s;  // negative dims: bits 3,4
  if (a & b & 0x20) s = 0.0f;           // null dim: bit 5
  return s;
}

// One FMA term, all indices template-constant.
template <int Q, int ALO, int AHI, int KK>
__device__ __forceinline__ void term(float xa, const float (&yr)[16], float (&acc)[16]) {
  constexpr int a = 4 * AHI + ALO;
  constexpr int b = 4 * (AHI ^ KK) + (ALO ^ Q);
  constexpr float sg = sign_ab(a, b);
  if constexpr (sg > 0.0f)      acc[KK] = fmaf( xa, yr[AHI ^ KK], acc[KK]);
  else if constexpr (sg < 0.0f) acc[KK] = fmaf(-xa, yr[AHI ^ KK], acc[KK]);
  // sg == 0: no code (null-dim annihilation)
}

template <int Q, int ALO, int AHI, int... KK>
__device__ __forceinline__ void terms(float xa, const float (&yr)[16], float (&acc)[16],
                                      std::integer_sequence<int, KK...>) {
  (term<Q, ALO, AHI, KK>(xa, yr, acc), ...);
}

template <int Q, int ALO, int... AHI>
__device__ __forceinline__ void stream_x(const float* __restrict__ xrow,
                                         const float (&yr)[16], float (&acc)[16],
                                         std::integer_sequence<int, AHI...>) {
  (terms<Q, ALO, AHI>(xrow[4 * AHI + ALO], yr, acc,
                      std::make_integer_sequence<int, 16>{}), ...);
}

template <int Q, int ALO, int... HH>
__device__ __forceinline__ void load_y(const float* __restrict__ yrow, float (&yr)[16],
                                       std::integer_sequence<int, HH...>) {
  ((yr[HH] = yrow[4 * HH + (ALO ^ Q)]), ...);
}

template <int Q, int ALO>
__device__ __forceinline__ void group(const float* __restrict__ xrow,
                                      const float* __restrict__ yrow, float (&acc)[16]) {
  float yr[16];  // fresh scope per group: 16 y regs live only within the group
  load_y<Q, ALO>(yrow, yr, std::make_integer_sequence<int, 16>{});
  stream_x<Q, ALO>(xrow, yr, acc, std::make_integer_sequence<int, 16>{});
}

template <int Q>
__device__ __forceinline__ void compute(const float* __restrict__ xrow,
                                        const float* __restrict__ yrow, float (&acc)[16]) {
  group<Q, 0>(xrow, yrow, acc);
  group<Q, 1>(xrow, yrow, acc);
  group<Q, 2>(xrow, yrow, acc);
  group<Q, 3>(xrow, yrow, acc);
}

__global__ __launch_bounds__(256) void clgp_kernel(const float* __restrict__ xg,
                                                   const float* __restrict__ yg,
                                                   float* __restrict__ og) {
  // Stride-65 rows: 65 % 32 == 1 -> per-lane scalar row reads are 2-way
  // bank-aliased (free, m136); stride 64 would be a 32-way conflict.
  __shared__ float xl[64 * 65];
  __shared__ float yl[64 * 65];

  const int t = threadIdx.x;
  const long tile = (long)blockIdx.x * 4096;  // 64 rows * 64 cols

  // ---- stage x,y: coalesced global float4 -> reg -> padded LDS ----
  const float4* x4 = (const float4*)(xg + tile);
  const float4* y4 = (const float4*)(yg + tile);
  float4 rx[4], ry[4];
#pragma unroll
  for (int p = 0; p < 4; ++p) {
    rx[p] = x4[t + p * 256];
    ry[p] = y4[t + p * 256];
  }
#pragma unroll
  for (int p = 0; p < 4; ++p) {
    const int v = t + p * 256;               // float4 index within tile
    const int w = (v >> 4) * 65 + (v & 15) * 4;
    xl[w + 0] = rx[p].x; xl[w + 1] = rx[p].y; xl[w + 2] = rx[p].z; xl[w + 3] = rx[p].w;
    yl[w + 0] = ry[p].x; yl[w + 1] = ry[p].y; yl[w + 2] = ry[p].z; yl[w + 3] = ry[p].w;
  }
  __syncthreads();

  const int lane = t & 63;  // batch row within tile
  const int q = t >> 6;     // wave id = k residue class mod 4 (wave-uniform)

  float acc[16];
#pragma unroll
  for (int i = 0; i < 16; ++i) acc[i] = 0.0f;

  const float* xrow = &xl[lane * 65];
  const float* yrow = &yl[lane * 65];
  switch (q) {  // wave-uniform -> no divergence
    case 0:  compute<0>(xrow, yrow, acc); break;
    case 1:  compute<1>(xrow, yrow, acc); break;
    case 2:  compute<2>(xrow, yrow, acc); break;
    default: compute<3>(xrow, yrow, acc); break;
  }

  __syncthreads();  // all waves done reading xl
  // transpose acc back through LDS (reuse xl) for coalesced float4 stores
#pragma unroll
  for (int kk = 0; kk < 16; ++kk) xl[lane * 65 + q + 4 * kk] = acc[kk];
  __syncthreads();

  float4* o4 = (float4*)(og + tile);
#pragma unroll
  for (int p = 0; p < 4; ++p) {
    const int v = t + p * 256;
    const int w = (v >> 4) * 65 + (v & 15) * 4;
    float4 o;
    o.x = xl[w + 0]; o.y = xl[w + 1]; o.z = xl[w + 2]; o.w = xl[w + 3];
    o4[v] = o;
  }
}

extern "C" void kernel_launch(void* const* d_in, const int* in_sizes, int n_in,
                              void* d_out, int out_size, void* d_ws, size_t ws_size,
                              hipStream_t stream) {
  const float* x = (const float*)d_in[0];
  const float* y = (const float*)d_in[1];
  float* out = (float*)d_out;
  const int n_batch = in_sizes[0] / 64;
  const int grid = n_batch / 64;  // 65536/64 = 1024 blocks, 256 threads
  clgp_kernel<<<grid, 256, 0, stream>>>(x, y, out);
}